// Round 5
// baseline (13547.374 us; speedup 1.0000x reference)
//
#include <hip/hip_runtime.h>

typedef _Float16 half_t;
typedef _Float16 f16x8 __attribute__((ext_vector_type(8)));
typedef _Float16 f16x4 __attribute__((ext_vector_type(4)));
typedef float f32x4 __attribute__((ext_vector_type(4)));
typedef unsigned int uint2v __attribute__((ext_vector_type(2)));

#define T_LEN 512
#define BATCH 128
#define INDIM 800
#define HID   400
#define NG    3200   // 2 dirs * 4H
#define KP    416    // recurrent K padded to 13*32
#define BPD   25     // blocks per direction
#define UPB   16     // units per block (64 gate rows)
#define NTH   512

// coherent-at-LLC access (bypass L1+L2) -----------------------------------
__device__ __forceinline__ f32x4 ld_coh_128(const void* p) {
    f32x4 r;
    asm volatile("global_load_dwordx4 %0, %1, off sc0 sc1" : "=v"(r) : "v"(p) : "memory");
    return r;
}
__device__ __forceinline__ void st_coh_64(void* p, uint2v v) {
    asm volatile("global_store_dwordx2 %0, %1, off sc0 sc1" :: "v"(p), "v"(v) : "memory");
}
__device__ __forceinline__ void st_coh_32(void* p, int v) {
    asm volatile("global_store_dword %0, %1, off sc0 sc1" :: "v"(p), "v"(v) : "memory");
}
__device__ __forceinline__ int ld_coh_32(const void* p) {
    int v;
    asm volatile("global_load_dword %0, %1, off sc0 sc1\ns_waitcnt vmcnt(0)"
                 : "=v"(v) : "v"(p) : "memory");
    return v;
}
// plain cached u16 load, result usable only after a vmcnt drain
#define GLD_U16(dst, ptr, offlit)                                            \
    asm volatile("global_load_ushort %0, %1, off offset:" #offlit            \
                 : "=v"(dst) : "v"(ptr) : "memory")

// ---------------- cast fp32 -> fp16 ----------------
__global__ void cast_f32_f16(const float* __restrict__ src, half_t* __restrict__ dst, size_t n) {
    size_t i = (size_t)blockIdx.x * blockDim.x + threadIdx.x;
    size_t stride = (size_t)gridDim.x * blockDim.x;
    for (; i < n; i += stride) dst[i] = (half_t)src[i];
}

// ---------------- input GEMM ----------------
// A[M=T*B, 800] @ W[3200, 800]^T, output TRANSPOSED per t-tile:
// gates_T[((t*3200)+n)*128 + b]   (fp16, fp32 accum)
__global__ __launch_bounds__(256)
void gemm_f16(const half_t* __restrict__ A, const half_t* __restrict__ Bw,
              half_t* __restrict__ C) {
    __shared__ half_t As[128 * 32];
    __shared__ half_t Bs[128 * 32];
    const int tid  = threadIdx.x;
    const int m0   = blockIdx.x * 128;     // m-tile == one t (128 batches)
    const int n0   = blockIdx.y * 128;
    const int w    = tid >> 6;
    const int lane = tid & 63;
    const int wm   = (w & 1) * 64;
    const int wn   = (w >> 1) * 64;
    const int lr   = lane & 15;
    const int kb   = (lane >> 4) * 8;

    f32x4 acc[4][4] = {};

    for (int k0 = 0; k0 < INDIM; k0 += 32) {
        __syncthreads();
        #pragma unroll
        for (int it = 0; it < 2; ++it) {
            int c   = tid + it * 256;      // 512 chunks of 8 halfs
            int row = c >> 2;
            int kp  = (c & 3) * 8;
            *(f16x8*)(As + row * 32 + kp) = *(const f16x8*)(A  + (size_t)(m0 + row) * INDIM + k0 + kp);
            *(f16x8*)(Bs + row * 32 + kp) = *(const f16x8*)(Bw + (size_t)(n0 + row) * INDIM + k0 + kp);
        }
        __syncthreads();
        f16x8 a[4], b[4];
        #pragma unroll
        for (int i = 0; i < 4; ++i) a[i] = *(const f16x8*)(As + (wm + i * 16 + lr) * 32 + kb);
        #pragma unroll
        for (int j = 0; j < 4; ++j) b[j] = *(const f16x8*)(Bs + (wn + j * 16 + lr) * 32 + kb);
        // swapped operands -> C row = n (gate row), col = m (batch)
        #pragma unroll
        for (int i = 0; i < 4; ++i)
            #pragma unroll
            for (int j = 0; j < 4; ++j)
                acc[i][j] = __builtin_amdgcn_mfma_f32_16x16x32_f16(b[j], a[i], acc[i][j], 0, 0, 0);
    }

    const int t  = blockIdx.x;
    const int lq = lane >> 4;
    #pragma unroll
    for (int i = 0; i < 4; ++i)
        #pragma unroll
        for (int j = 0; j < 4; ++j)
            #pragma unroll
            for (int r = 0; r < 4; ++r) {
                int n  = n0 + wn + j * 16 + lq * 4 + r;
                int bb = wm + i * 16 + lr;
                C[((size_t)t * NG + n) * BATCH + bb] = (half_t)acc[i][j][r];
            }
}

// ---------------- persistent bidirectional scan (one layer) ----------------
// grid = 50 blocks x 512 threads: [0,25) fwd, [25,50) bwd; each owns 16 units
// (64 gate rows). h exchange via sc0sc1 (LLC-coherent); flag-array barrier;
// clean spin (no outstanding VMEM besides the poll).
__global__ __launch_bounds__(512)
void scan_kernel(const float* __restrict__ Whh_all, const float* __restrict__ bih,
                 const float* __restrict__ bhh, const half_t* __restrict__ gates,
                 const int* __restrict__ bs, half_t* __restrict__ h_pub,
                 int* __restrict__ flags,
                 half_t* __restrict__ out16, float* __restrict__ out32, int layer) {
    __shared__ half_t Wsh[64][424];
    __shared__ float  Gsh[64][132];
    __shared__ int    bs_sh[T_LEN];

    const int tid = threadIdx.x;
    const int d   = blockIdx.x / BPD;
    const int blk = blockIdx.x % BPD;
    const int u0  = blk * UPB;
    const float* Wbase = Whh_all + (size_t)(layer * 2 + d) * 1600 * HID;

    // stage 64 Whh rows (4 types x 16 units), fp32 -> fp16, zero-pad K to 416
    for (int idx = tid; idx < 64 * KP; idx += NTH) {
        int g = idx / KP, k = idx - g * KP;
        int type = g >> 4, usub = g & 15;
        float v = (k < HID) ? Wbase[(size_t)(type * HID + u0 + usub) * HID + k] : 0.f;
        Wsh[g][k] = (half_t)v;
    }
    for (int i = tid; i < T_LEN; i += NTH) bs_sh[i] = bs[i];

    const int lane = tid & 63, w = tid >> 6;
    const int gt = w >> 2, bt = w & 3;          // gate-tile, batch-tile of this wave
    const int lr = lane & 15, kq = (lane >> 4) * 8;
    const int b = tid & 127, s = tid >> 7;      // cell-phase identity (4 units each)

    float bias[4][4];
    float c_reg[4] = {0.f, 0.f, 0.f, 0.f}, h_reg[4] = {0.f, 0.f, 0.f, 0.f};
    #pragma unroll
    for (int q = 0; q < 4; ++q) {
        int usub = 4 * s + q;
        #pragma unroll
        for (int ty = 0; ty < 4; ++ty) {
            size_t bi = (size_t)(layer * 2 + d) * 1600 + ty * HID + u0 + usub;
            bias[q][ty] = bih[bi] + bhh[bi];
        }
    }

    const long gstep = (long)(d ? -1 : 1) * (long)NG * BATCH;
    const long ostep = (long)(d ? -1 : 1) * (long)BATCH * 800;
    const int  t0p   = d ? (T_LEN - 1) : 0;
    const half_t* gptr = gates + (size_t)t0p * NG * BATCH + (size_t)d * 1600 * BATCH
                       + (size_t)(u0 + 4 * s) * BATCH + b;
    float*  op32 = out32 ? out32 + (size_t)t0p * BATCH * 800 + (size_t)b * 800 + d * HID + u0 + 4 * s
                         : (float*)nullptr;
    half_t* op16 = out16 ? out16 + (size_t)t0p * BATCH * 800 + (size_t)b * 800 + d * HID + u0 + 4 * s
                         : (half_t*)nullptr;

    // raw u16 gate registers: [q][ty]; converted at use after a drain
    int rawc[4][4], rawn[4][4];
#define GPRE_ISSUE(dstv, base) do {                                          \
        _Pragma("unroll") for (int ty_ = 0; ty_ < 4; ++ty_) {                \
            const half_t* pt_ = (base) + (size_t)ty_ * (HID * BATCH);        \
            GLD_U16(dstv[0][ty_], pt_, 0);                                   \
            GLD_U16(dstv[1][ty_], pt_, 256);                                 \
            GLD_U16(dstv[2][ty_], pt_, 512);                                 \
            GLD_U16(dstv[3][ty_], pt_, 768);                                 \
        }                                                                    \
    } while (0)

    __syncthreads();
    int bst = bs_sh[t0p];
    bool bact = b < bst;
    if (bact) GPRE_ISSUE(rawc, gptr);   // drained by first top-of-loop wait

    int cur = 0;

    for (int t = 0; t < T_LEN; ++t) {
        const bool last = (t == T_LEN - 1);
        const half_t* hcur = h_pub + (size_t)(cur * 2 + d) * BATCH * KP;

        // ---- issue coherent h loads (oldest), then next-step gate prefetch ----
        const bool act0 = (bt * 32) < bst;
        const bool act1 = (bt * 32 + 16) < bst;
        f32x4 hb0[13], hb1[13];
        const half_t* p0 = hcur + (size_t)(bt * 32 + lr) * KP + kq;
        const half_t* p1 = p0 + 16 * KP;
        if (act0) {
            #pragma unroll
            for (int ks = 0; ks < 13; ++ks) hb0[ks] = ld_coh_128(p0 + ks * 32);
        }
        if (act1) {
            #pragma unroll
            for (int ks = 0; ks < 13; ++ks) hb1[ks] = ld_coh_128(p1 + ks * 32);
        }
        const int bst_next = last ? 0 : bs_sh[d ? (T_LEN - 2 - t) : (t + 1)];
        const half_t* gp2 = gptr + gstep;
        if (!last && b < bst_next) GPRE_ISSUE(rawn, gp2);

        // counted drain: h loads complete; gate prefetch (16 newest) may fly on
        const bool gq = !last && (bst_next > ((w & 1) * 64));   // wave-uniform
        if (gq) asm volatile("s_waitcnt vmcnt(16)" ::: "memory");
        else    asm volatile("s_waitcnt vmcnt(0)"  ::: "memory");
        __builtin_amdgcn_sched_barrier(0);

        // ---- phase 1: MFMA  C[64 gates][128 b], this wave: [32gt..+31][32bt..+31]
        f32x4 acc[2][2] = {};
        if (act0) {
            #pragma unroll
            for (int ks = 0; ks < 13; ++ks) {
                f16x8 a0 = *(const f16x8*)(&Wsh[32 * gt + lr][kq + ks * 32]);
                f16x8 a1 = *(const f16x8*)(&Wsh[32 * gt + 16 + lr][kq + ks * 32]);
                f16x8 b0 = __builtin_bit_cast(f16x8, hb0[ks]);
                acc[0][0] = __builtin_amdgcn_mfma_f32_16x16x32_f16(a0, b0, acc[0][0], 0, 0, 0);
                acc[1][0] = __builtin_amdgcn_mfma_f32_16x16x32_f16(a1, b0, acc[1][0], 0, 0, 0);
                if (act1) {
                    f16x8 b1 = __builtin_bit_cast(f16x8, hb1[ks]);
                    acc[0][1] = __builtin_amdgcn_mfma_f32_16x16x32_f16(a0, b1, acc[0][1], 0, 0, 0);
                    acc[1][1] = __builtin_amdgcn_mfma_f32_16x16x32_f16(a1, b1, acc[1][1], 0, 0, 0);
                }
            }
        }
        const int crow = (lane >> 4) * 4;
        #pragma unroll
        for (int i = 0; i < 2; ++i) {
            if (act0) {
                #pragma unroll
                for (int r = 0; r < 4; ++r)
                    Gsh[32 * gt + i * 16 + crow + r][32 * bt + lr] = acc[i][0][r];
            }
            if (act1) {
                #pragma unroll
                for (int r = 0; r < 4; ++r)
                    Gsh[32 * gt + i * 16 + crow + r][32 * bt + 16 + lr] = acc[i][1][r];
            }
        }
        __syncthreads();

        // ---- phase 2: LSTM cell, 4 adjacent units per thread ----
        if (bact) {
            #pragma unroll
            for (int q = 0; q < 4; ++q) {
                int u = 4 * s + q;
                float gI = Gsh[u][b]      + (float)__builtin_bit_cast(half_t, (unsigned short)rawc[q][0]) + bias[q][0];
                float gF = Gsh[16 + u][b] + (float)__builtin_bit_cast(half_t, (unsigned short)rawc[q][1]) + bias[q][1];
                float gG = Gsh[32 + u][b] + (float)__builtin_bit_cast(half_t, (unsigned short)rawc[q][2]) + bias[q][2];
                float gO = Gsh[48 + u][b] + (float)__builtin_bit_cast(half_t, (unsigned short)rawc[q][3]) + bias[q][3];
                float iv = 1.f / (1.f + __expf(-gI));
                float fv = 1.f / (1.f + __expf(-gF));
                float gv = 1.f - 2.f / (1.f + __expf(2.f * gG));
                float ov = 1.f / (1.f + __expf(-gO));
                float cn = fv * c_reg[q] + iv * gv;
                float hnew = ov * (1.f - 2.f / (1.f + __expf(2.f * cn)));
                c_reg[q] = cn; h_reg[q] = hnew;
            }
            if (!last) {
                half_t* hn = h_pub + (size_t)((cur ^ 1) * 2 + d) * BATCH * KP;
                f16x4 hv4;
                hv4[0] = (half_t)h_reg[0]; hv4[1] = (half_t)h_reg[1];
                hv4[2] = (half_t)h_reg[2]; hv4[3] = (half_t)h_reg[3];
                st_coh_64(hn + (size_t)b * KP + u0 + 4 * s, __builtin_bit_cast(uint2v, hv4));
            }
            if (op32) { f32x4 o4 = {h_reg[0], h_reg[1], h_reg[2], h_reg[3]}; *(f32x4*)op32 = o4; }
            else {
                f16x4 o4;
                o4[0] = (half_t)h_reg[0]; o4[1] = (half_t)h_reg[1];
                o4[2] = (half_t)h_reg[2]; o4[3] = (half_t)h_reg[3];
                *(f16x4*)op16 = o4;
            }
        } else {
            if (op32) { f32x4 z = {0.f, 0.f, 0.f, 0.f}; *(f32x4*)op32 = z; }
            else { f16x4 z; z[0] = z[1] = z[2] = z[3] = (half_t)0.f; *(f16x4*)op16 = z; }
        }
        if (op32) op32 += ostep; else op16 += ostep;

        // drain publish + outputs + in-flight gate prefetch
        asm volatile("s_waitcnt vmcnt(0)" ::: "memory");

        if (!last) {
            __syncthreads();                    // all h stores of this block drained
            if (tid == 0) st_coh_32(&flags[d * 64 + blk], t + 1);

            // every wave spins independently; polls are the ONLY outstanding VMEM
            {
                const int* fp = flags + d * 64 + lane;
                int pred;
                do {
                    int v = (lane < BPD) ? ld_coh_32(fp) : 0x7fffffff;
                    pred = (v >= t + 1);
                } while (!__all(pred));
            }

            // rotate pipelined state (no barrier needed: Gsh reads done pre-flag)
            gptr = gp2;
            bst = bst_next; bact = b < bst;
            #pragma unroll
            for (int q = 0; q < 4; ++q)
                #pragma unroll
                for (int ty = 0; ty < 4; ++ty) rawc[q][ty] = rawn[q][ty];
        }
        cur ^= 1;
    }
#undef GPRE_ISSUE
}

// ---------------- host ----------------
extern "C" void kernel_launch(void* const* d_in, const int* in_sizes, int n_in,
                              void* d_out, int out_size, void* d_ws, size_t ws_size,
                              hipStream_t stream) {
    const float* x    = (const float*)d_in[0];
    const float* Wih  = (const float*)d_in[1];
    const float* Whh  = (const float*)d_in[2];
    const float* bih  = (const float*)d_in[3];
    const float* bhh  = (const float*)d_in[4];
    const int*   bs   = (const int*)d_in[5];
    float*       out  = (float*)d_out;

    char* ws = (char*)d_ws;
    const size_t XBUF_B  = (size_t)T_LEN * BATCH * INDIM * 2;      // 104,857,600
    const size_t WIH_B   = (size_t)3 * 2 * 1600 * INDIM * 2;       //  15,360,000
    const size_t GATES_B = (size_t)T_LEN * NG * BATCH * 2;         // 419,430,400
    const size_t HPUB_B  = (size_t)2 * 2 * BATCH * KP * 2;         //     425,984

    half_t* xbuf0 = (half_t*)(ws);
    half_t* xbuf1 = (half_t*)(ws + XBUF_B);
    half_t* Wih16 = (half_t*)(ws + 2 * XBUF_B);
    half_t* gates = (half_t*)(ws + 2 * XBUF_B + WIH_B);
    half_t* h_pub = (half_t*)(ws + 2 * XBUF_B + WIH_B + GATES_B);
    int*    flags = (int*)   (ws + 2 * XBUF_B + WIH_B + GATES_B + HPUB_B);
    (void)ws_size; (void)in_sizes; (void)n_in; (void)out_size;

    cast_f32_f16<<<2048, 256, 0, stream>>>(x,   xbuf0, (size_t)T_LEN * BATCH * INDIM);
    cast_f32_f16<<<2048, 256, 0, stream>>>(Wih, Wih16, (size_t)3 * 2 * 1600 * INDIM);

    for (int l = 0; l < 3; ++l) {
        const half_t* xin    = (l == 0) ? xbuf0 : ((l == 1) ? xbuf1 : xbuf0);
        half_t*       xout16 = (l == 0) ? xbuf1 : ((l == 1) ? xbuf0 : (half_t*)nullptr);
        float*        out32  = (l == 2) ? out : (float*)nullptr;

        gemm_f16<<<dim3(512, 25), 256, 0, stream>>>(xin, Wih16 + (size_t)l * NG * INDIM, gates);

        // zero h double-buffers + barrier flags
        hipMemsetAsync(h_pub, 0, HPUB_B + 512, stream);

        const float* WhhA = Whh; const float* bihA = bih; const float* bhhA = bhh;
        const half_t* gatesA = gates; const int* bsA = bs; half_t* hpubA = h_pub;
        int* flagsA = flags; int layer = l;
        void* args[] = {(void*)&WhhA, (void*)&bihA, (void*)&bhhA, (void*)&gatesA,
                        (void*)&bsA, (void*)&hpubA, (void*)&flagsA,
                        (void*)&xout16, (void*)&out32, (void*)&layer};
        hipLaunchCooperativeKernel((void*)scan_kernel, dim3(2 * BPD), dim3(NTH), args, 0, stream);
    }
}

// Round 6
// 11929.667 us; speedup vs baseline: 1.1356x; 1.1356x over previous
//
#include <hip/hip_runtime.h>

typedef _Float16 half_t;
typedef _Float16 f16x8 __attribute__((ext_vector_type(8)));
typedef _Float16 f16x4 __attribute__((ext_vector_type(4)));
typedef float f32x4 __attribute__((ext_vector_type(4)));
typedef int   i32x4 __attribute__((ext_vector_type(4)));
typedef unsigned int uint2v __attribute__((ext_vector_type(2)));

#define T_LEN 512
#define BATCH 128
#define INDIM 800
#define HID   400
#define NG    3200   // 2 dirs * 4H
#define KP    416    // recurrent K padded to 13*32
#define BPD   50     // blocks per direction
#define UPB   8      // units per block (32 gate rows)
#define WPD   200    // waves per direction (BPD*4)

// coherent-at-LLC access (bypass L1+L2) -----------------------------------
__device__ __forceinline__ f32x4 ld_coh_128(const void* p) {
    f32x4 r;
    asm volatile("global_load_dwordx4 %0, %1, off sc0 sc1" : "=v"(r) : "v"(p) : "memory");
    return r;
}
__device__ __forceinline__ i32x4 ld_coh_128i(const void* p) {
    i32x4 r;
    asm volatile("global_load_dwordx4 %0, %1, off sc0 sc1\ns_waitcnt vmcnt(0)"
                 : "=v"(r) : "v"(p) : "memory");
    return r;
}
__device__ __forceinline__ void st_coh_64(void* p, uint2v v) {
    asm volatile("global_store_dwordx2 %0, %1, off sc0 sc1" :: "v"(p), "v"(v) : "memory");
}
__device__ __forceinline__ void st_coh_32(void* p, int v) {
    asm volatile("global_store_dword %0, %1, off sc0 sc1" :: "v"(p), "v"(v) : "memory");
}
// plain cached u16 load, result usable only after a vmcnt drain
#define GLD_U16(dst, ptr, offlit)                                            \
    asm volatile("global_load_ushort %0, %1, off offset:" #offlit            \
                 : "=v"(dst) : "v"(ptr) : "memory")

// ---------------- cast fp32 -> fp16 ----------------
__global__ void cast_f32_f16(const float* __restrict__ src, half_t* __restrict__ dst, size_t n) {
    size_t i = (size_t)blockIdx.x * blockDim.x + threadIdx.x;
    size_t stride = (size_t)gridDim.x * blockDim.x;
    for (; i < n; i += stride) dst[i] = (half_t)src[i];
}

// ---------------- input GEMM ----------------
// A[M=T*B, 800] @ W[3200, 800]^T, output TRANSPOSED per t-tile:
// gates_T[((t*3200)+n)*128 + b]   (fp16, fp32 accum)
__global__ __launch_bounds__(256)
void gemm_f16(const half_t* __restrict__ A, const half_t* __restrict__ Bw,
              half_t* __restrict__ C) {
    __shared__ half_t As[128 * 32];
    __shared__ half_t Bs[128 * 32];
    const int tid  = threadIdx.x;
    const int m0   = blockIdx.x * 128;     // m-tile == one t (128 batches)
    const int n0   = blockIdx.y * 128;
    const int w    = tid >> 6;
    const int lane = tid & 63;
    const int wm   = (w & 1) * 64;
    const int wn   = (w >> 1) * 64;
    const int lr   = lane & 15;
    const int kb   = (lane >> 4) * 8;

    f32x4 acc[4][4] = {};

    for (int k0 = 0; k0 < INDIM; k0 += 32) {
        __syncthreads();
        #pragma unroll
        for (int it = 0; it < 2; ++it) {
            int c   = tid + it * 256;      // 512 chunks of 8 halfs
            int row = c >> 2;
            int kp  = (c & 3) * 8;
            *(f16x8*)(As + row * 32 + kp) = *(const f16x8*)(A  + (size_t)(m0 + row) * INDIM + k0 + kp);
            *(f16x8*)(Bs + row * 32 + kp) = *(const f16x8*)(Bw + (size_t)(n0 + row) * INDIM + k0 + kp);
        }
        __syncthreads();
        f16x8 a[4], b[4];
        #pragma unroll
        for (int i = 0; i < 4; ++i) a[i] = *(const f16x8*)(As + (wm + i * 16 + lr) * 32 + kb);
        #pragma unroll
        for (int j = 0; j < 4; ++j) b[j] = *(const f16x8*)(Bs + (wn + j * 16 + lr) * 32 + kb);
        // swapped operands -> C row = n (gate row), col = m (batch)
        #pragma unroll
        for (int i = 0; i < 4; ++i)
            #pragma unroll
            for (int j = 0; j < 4; ++j)
                acc[i][j] = __builtin_amdgcn_mfma_f32_16x16x32_f16(b[j], a[i], acc[i][j], 0, 0, 0);
    }

    const int t  = blockIdx.x;
    const int lq = lane >> 4;
    #pragma unroll
    for (int i = 0; i < 4; ++i)
        #pragma unroll
        for (int j = 0; j < 4; ++j)
            #pragma unroll
            for (int r = 0; r < 4; ++r) {
                int n  = n0 + wn + j * 16 + lq * 4 + r;
                int bb = wm + i * 16 + lr;
                C[((size_t)t * NG + n) * BATCH + bb] = (half_t)acc[i][j][r];
            }
}

// ---------------- persistent bidirectional scan (one layer) ----------------
// grid = 100 blocks x 256 thr: [0,50) fwd, [50,100) bwd; each block owns 8
// units (32 gate rows). Waves are fully autonomous: no per-step __syncthreads.
// Wave w handles batch tile [32w,32w+32): MFMA all 32 gate rows for its tile,
// shfl-exchange gate types within the wave, run the cell, publish h + its own
// flag. Barrier = 200 per-wave flags polled with one dwordx4 per lane.
__global__ __launch_bounds__(256)
void scan_kernel(const float* __restrict__ Whh_all, const float* __restrict__ bih,
                 const float* __restrict__ bhh, const half_t* __restrict__ gates,
                 const int* __restrict__ bs, half_t* __restrict__ h_pub,
                 int* __restrict__ flags,
                 half_t* __restrict__ out16, float* __restrict__ out32, int layer) {
    __shared__ half_t Wsh[32][424];
    __shared__ int    bs_sh[T_LEN];

    const int tid = threadIdx.x;
    const int d   = blockIdx.x / BPD;
    const int blk = blockIdx.x % BPD;
    const int u0  = blk * UPB;
    const float* Wbase = Whh_all + (size_t)(layer * 2 + d) * 1600 * HID;

    // stage 32 Whh rows (4 types x 8 units), fp32 -> fp16, zero-pad K to 416
    for (int idx = tid; idx < 32 * KP; idx += 256) {
        int g = idx / KP, k = idx - g * KP;
        int type = g >> 3, usub = g & 7;
        float v = (k < HID) ? Wbase[(size_t)(type * HID + u0 + usub) * HID + k] : 0.f;
        Wsh[g][k] = (half_t)v;
    }
    for (int i = tid; i < T_LEN; i += 256) bs_sh[i] = bs[i];

    const int lane = tid & 63, w = tid >> 6;          // w = batch tile
    const int lr = lane & 15, kq = (lane >> 4) * 8;
    const int g  = lane >> 4;                          // 4-lane-group id
    const int gHalf = g & 1;                           // unit half: 4*gHalf..+3
    const int jKeep = g >> 1;                          // kept batch 16-col
    const int bcol  = w * 32 + 16 * jKeep + lr;        // this lane's batch
    const int uu    = 4 * gHalf;                       // local unit base

    float bias[4][4];
    float c_reg[4] = {0.f, 0.f, 0.f, 0.f}, h_reg[4] = {0.f, 0.f, 0.f, 0.f};
    #pragma unroll
    for (int q = 0; q < 4; ++q) {
        #pragma unroll
        for (int ty = 0; ty < 4; ++ty) {
            size_t bi = (size_t)(layer * 2 + d) * 1600 + ty * HID + u0 + uu + q;
            bias[q][ty] = bih[bi] + bhh[bi];
        }
    }

    const long gstep = (long)(d ? -1 : 1) * (long)NG * BATCH;
    const long ostep = (long)(d ? -1 : 1) * (long)BATCH * 800;
    const int  t0p   = d ? (T_LEN - 1) : 0;
    const half_t* gptr = gates + (size_t)t0p * NG * BATCH + (size_t)d * 1600 * BATCH
                       + (size_t)(u0 + uu) * BATCH + bcol;
    float*  op32 = out32 ? out32 + (size_t)t0p * BATCH * 800 + (size_t)bcol * 800 + d * HID + u0 + uu
                         : (float*)nullptr;
    half_t* op16 = out16 ? out16 + (size_t)t0p * BATCH * 800 + (size_t)bcol * 800 + d * HID + u0 + uu
                         : (half_t*)nullptr;

    // raw u16 gate registers: [q][ty]; converted at use after a drain
    int rawc[4][4], rawn[4][4];
#define GPRE_ISSUE(dstv, base) do {                                          \
        _Pragma("unroll") for (int ty_ = 0; ty_ < 4; ++ty_) {                \
            const half_t* pt_ = (base) + (size_t)ty_ * (HID * BATCH);        \
            GLD_U16(dstv[0][ty_], pt_, 0);                                   \
            GLD_U16(dstv[1][ty_], pt_, 256);                                 \
            GLD_U16(dstv[2][ty_], pt_, 512);                                 \
            GLD_U16(dstv[3][ty_], pt_, 768);                                 \
        }                                                                    \
    } while (0)

    __syncthreads();
    int bst = bs_sh[t0p];
    bool active = bcol < bst;
    if (active) GPRE_ISSUE(rawc, gptr);   // drained by first top-of-loop wait

    int* const myflag = flags + d * 256 + blk * 4 + w;
    const int* const pollp = flags + d * 256 + lane * 4;
    int cur = 0;

    for (int t = 0; t < T_LEN; ++t) {
        const bool last = (t == T_LEN - 1);
        const half_t* hcur = h_pub + (size_t)(cur * 2 + d) * BATCH * KP;

        // ---- coherent h loads for this wave's batch tile ----
        const bool act0 = (w * 32) < bst;
        const bool act1 = (w * 32 + 16) < bst;
        f32x4 hb0[13], hb1[13];
        const half_t* p0 = hcur + (size_t)(w * 32 + lr) * KP + kq;
        const half_t* p1 = p0 + 16 * KP;
        if (act0) {
            #pragma unroll
            for (int ks = 0; ks < 13; ++ks) hb0[ks] = ld_coh_128(p0 + ks * 32);
        }
        if (act1) {
            #pragma unroll
            for (int ks = 0; ks < 13; ++ks) hb1[ks] = ld_coh_128(p1 + ks * 32);
        }
        asm volatile("s_waitcnt vmcnt(0)" ::: "memory");
        __builtin_amdgcn_sched_barrier(0);

        // ---- MFMA: 32 gate rows x this wave's 32 batches ----
        f32x4 acc[2][2] = {};
        if (act0) {
            #pragma unroll
            for (int ks = 0; ks < 13; ++ks) {
                f16x8 a0 = *(const f16x8*)(&Wsh[lr][kq + ks * 32]);
                f16x8 a1 = *(const f16x8*)(&Wsh[16 + lr][kq + ks * 32]);
                f16x8 b0 = __builtin_bit_cast(f16x8, hb0[ks]);
                acc[0][0] = __builtin_amdgcn_mfma_f32_16x16x32_f16(a0, b0, acc[0][0], 0, 0, 0);
                acc[1][0] = __builtin_amdgcn_mfma_f32_16x16x32_f16(a1, b0, acc[1][0], 0, 0, 0);
                if (act1) {
                    f16x8 b1 = __builtin_bit_cast(f16x8, hb1[ks]);
                    acc[0][1] = __builtin_amdgcn_mfma_f32_16x16x32_f16(a0, b1, acc[0][1], 0, 0, 0);
                    acc[1][1] = __builtin_amdgcn_mfma_f32_16x16x32_f16(a1, b1, acc[1][1], 0, 0, 0);
                }
            }
        }

        // ---- in-wave gate-type exchange (pairs g <-> g^2), no LDS ----
        // lane keeps batch col jKeep; sends the other col's acc to partner.
        f32x4 send0 = jKeep ? acc[0][0] : acc[0][1];
        f32x4 send1 = jKeep ? acc[1][0] : acc[1][1];
        f32x4 recv0, recv1;
        #pragma unroll
        for (int k = 0; k < 4; ++k) {
            recv0[k] = __shfl_xor(send0[k], 32, 64);
            recv1[k] = __shfl_xor(send1[k], 32, 64);
        }
        // per lane: all 4 gate types for units u0+uu..+3, batch bcol
        f32x4 vI = jKeep ? recv0     : acc[0][0];
        f32x4 vF = jKeep ? acc[0][1] : recv0;
        f32x4 vG = jKeep ? recv1     : acc[1][0];
        f32x4 vO = jKeep ? acc[1][1] : recv1;

        // ---- LSTM cell: 4 units for this lane's batch ----
        if (active) {
            #pragma unroll
            for (int q = 0; q < 4; ++q) {
                float gI = vI[q] + (float)__builtin_bit_cast(half_t, (unsigned short)rawc[q][0]) + bias[q][0];
                float gF = vF[q] + (float)__builtin_bit_cast(half_t, (unsigned short)rawc[q][1]) + bias[q][1];
                float gG = vG[q] + (float)__builtin_bit_cast(half_t, (unsigned short)rawc[q][2]) + bias[q][2];
                float gO = vO[q] + (float)__builtin_bit_cast(half_t, (unsigned short)rawc[q][3]) + bias[q][3];
                float iv = 1.f / (1.f + __expf(-gI));
                float fv = 1.f / (1.f + __expf(-gF));
                float gv = 1.f - 2.f / (1.f + __expf(2.f * gG));
                float ov = 1.f / (1.f + __expf(-gO));
                float cn = fv * c_reg[q] + iv * gv;
                float hnew = ov * (1.f - 2.f / (1.f + __expf(2.f * cn)));
                c_reg[q] = cn; h_reg[q] = hnew;
            }
            // publish h (skipped at last step)
            if (!last) {
                half_t* hn = h_pub + (size_t)((cur ^ 1) * 2 + d) * BATCH * KP;
                f16x4 hv4;
                hv4[0] = (half_t)h_reg[0]; hv4[1] = (half_t)h_reg[1];
                hv4[2] = (half_t)h_reg[2]; hv4[3] = (half_t)h_reg[3];
                st_coh_64(hn + (size_t)bcol * KP + u0 + uu, __builtin_bit_cast(uint2v, hv4));
            }
        }

        // ---- drain h store; signal this wave's flag ----
        if (!last) {
            asm volatile("s_waitcnt vmcnt(0)" ::: "memory");
            if (lane == 0) st_coh_32(myflag, t + 1);
        }

        // ---- output stores + next gate prefetch (inside spin window) ----
        if (active) {
            if (op32) { f32x4 o4 = {h_reg[0], h_reg[1], h_reg[2], h_reg[3]}; *(f32x4*)op32 = o4; }
            else {
                f16x4 o4;
                o4[0] = (half_t)h_reg[0]; o4[1] = (half_t)h_reg[1];
                o4[2] = (half_t)h_reg[2]; o4[3] = (half_t)h_reg[3];
                *(f16x4*)op16 = o4;
            }
        } else {
            if (op32) { f32x4 z = {0.f, 0.f, 0.f, 0.f}; *(f32x4*)op32 = z; }
            else { f16x4 z; z[0] = z[1] = z[2] = z[3] = (half_t)0.f; *(f16x4*)op16 = z; }
        }
        if (op32) op32 += ostep; else op16 += ostep;

        if (!last) {
            const int bst_next = bs_sh[d ? (T_LEN - 2 - t) : (t + 1)];
            const half_t* gp2 = gptr + gstep;
            if (bcol < bst_next) GPRE_ISSUE(rawn, gp2);

            // spin: each lane checks 4 flags with one coherent dwordx4
            int ok;
            do {
                i32x4 v = ld_coh_128i(pollp);
                ok = 1;
                #pragma unroll
                for (int k = 0; k < 4; ++k) {
                    int f = lane * 4 + k;
                    ok &= (f >= WPD) | (v[k] >= t + 1);
                }
            } while (!__all(ok));

            gptr = gp2;
            bst = bst_next; active = bcol < bst;
            #pragma unroll
            for (int q = 0; q < 4; ++q)
                #pragma unroll
                for (int ty = 0; ty < 4; ++ty) rawc[q][ty] = rawn[q][ty];
        }
        cur ^= 1;
    }
#undef GPRE_ISSUE
}

// ---------------- host ----------------
extern "C" void kernel_launch(void* const* d_in, const int* in_sizes, int n_in,
                              void* d_out, int out_size, void* d_ws, size_t ws_size,
                              hipStream_t stream) {
    const float* x    = (const float*)d_in[0];
    const float* Wih  = (const float*)d_in[1];
    const float* Whh  = (const float*)d_in[2];
    const float* bih  = (const float*)d_in[3];
    const float* bhh  = (const float*)d_in[4];
    const int*   bs   = (const int*)d_in[5];
    float*       out  = (float*)d_out;

    char* ws = (char*)d_ws;
    const size_t XBUF_B  = (size_t)T_LEN * BATCH * INDIM * 2;      // 104,857,600
    const size_t WIH_B   = (size_t)3 * 2 * 1600 * INDIM * 2;       //  15,360,000
    const size_t GATES_B = (size_t)T_LEN * NG * BATCH * 2;         // 419,430,400
    const size_t HPUB_B  = (size_t)2 * 2 * BATCH * KP * 2;         //     425,984

    half_t* xbuf0 = (half_t*)(ws);
    half_t* xbuf1 = (half_t*)(ws + XBUF_B);
    half_t* Wih16 = (half_t*)(ws + 2 * XBUF_B);
    half_t* gates = (half_t*)(ws + 2 * XBUF_B + WIH_B);
    half_t* h_pub = (half_t*)(ws + 2 * XBUF_B + WIH_B + GATES_B);
    int*    flags = (int*)   (ws + 2 * XBUF_B + WIH_B + GATES_B + HPUB_B);
    (void)ws_size; (void)in_sizes; (void)n_in; (void)out_size;

    cast_f32_f16<<<2048, 256, 0, stream>>>(x,   xbuf0, (size_t)T_LEN * BATCH * INDIM);
    cast_f32_f16<<<2048, 256, 0, stream>>>(Wih, Wih16, (size_t)3 * 2 * 1600 * INDIM);

    for (int l = 0; l < 3; ++l) {
        const half_t* xin    = (l == 0) ? xbuf0 : ((l == 1) ? xbuf1 : xbuf0);
        half_t*       xout16 = (l == 0) ? xbuf1 : ((l == 1) ? xbuf0 : (half_t*)nullptr);
        float*        out32  = (l == 2) ? out : (float*)nullptr;

        gemm_f16<<<dim3(512, 25), 256, 0, stream>>>(xin, Wih16 + (size_t)l * NG * INDIM, gates);

        // zero h double-buffers + per-wave flag arrays (2 dirs x 256 ints)
        hipMemsetAsync(h_pub, 0, HPUB_B + 2048, stream);

        const float* WhhA = Whh; const float* bihA = bih; const float* bhhA = bhh;
        const half_t* gatesA = gates; const int* bsA = bs; half_t* hpubA = h_pub;
        int* flagsA = flags; int layer = l;
        void* args[] = {(void*)&WhhA, (void*)&bihA, (void*)&bhhA, (void*)&gatesA,
                        (void*)&bsA, (void*)&hpubA, (void*)&flagsA,
                        (void*)&xout16, (void*)&out32, (void*)&layer};
        hipLaunchCooperativeKernel((void*)scan_kernel, dim3(2 * BPD), dim3(256), args, 0, stream);
    }
}

// Round 9
// 11222.402 us; speedup vs baseline: 1.2072x; 1.0630x over previous
//
#include <hip/hip_runtime.h>

typedef _Float16 half_t;
typedef _Float16 f16x8 __attribute__((ext_vector_type(8)));
typedef _Float16 f16x4 __attribute__((ext_vector_type(4)));
typedef float f32x4 __attribute__((ext_vector_type(4)));
typedef unsigned int uint2v __attribute__((ext_vector_type(2)));

#define T_LEN 512
#define BATCH 128
#define INDIM 800
#define HID   400
#define NG    3200   // 2 dirs * 4H
#define KP    416    // recurrent K padded to 13*32
#define UPG   16     // units per block
#define NGRP  25     // unit-group blocks per (dir, batch-tile)
#define CT    32     // batch-tile size
#define NCT   4      // batch tiles
#define WSTR  424    // Wsh row stride in halfs (848 B: 16B-aligned for b128)

// coherent-at-LLC access (bypass L1+L2) -----------------------------------
__device__ __forceinline__ f32x4 ld_coh_128(const void* p) {
    f32x4 r;
    asm volatile("global_load_dwordx4 %0, %1, off sc0 sc1" : "=v"(r) : "v"(p) : "memory");
    return r;
}
__device__ __forceinline__ void st_coh_64(void* p, uint2v v) {
    asm volatile("global_store_dwordx2 %0, %1, off sc0 sc1" :: "v"(p), "v"(v) : "memory");
}
__device__ __forceinline__ void st_coh_32(void* p, int v) {
    asm volatile("global_store_dword %0, %1, off sc0 sc1" :: "v"(p), "v"(v) : "memory");
}
__device__ __forceinline__ int ld_coh_32(const void* p) {
    int v;
    asm volatile("global_load_dword %0, %1, off sc0 sc1\ns_waitcnt vmcnt(0)"
                 : "=v"(v) : "v"(p) : "memory");
    return v;
}

// ---------------- cast fp32 -> fp16 ----------------
__global__ void cast_f32_f16(const float* __restrict__ src, half_t* __restrict__ dst, size_t n) {
    size_t i = (size_t)blockIdx.x * blockDim.x + threadIdx.x;
    size_t stride = (size_t)gridDim.x * blockDim.x;
    for (; i < n; i += stride) dst[i] = (half_t)src[i];
}

// ---------------- input GEMM ----------------
// A[M=T*B, 800] @ W[3200, 800]^T, output TRANSPOSED per t-tile:
// gates_T[((t*3200)+n)*128 + b]   (fp16, fp32 accum)
__global__ __launch_bounds__(256)
void gemm_f16(const half_t* __restrict__ A, const half_t* __restrict__ Bw,
              half_t* __restrict__ C) {
    __shared__ half_t As[128 * 32];
    __shared__ half_t Bs[128 * 32];
    const int tid  = threadIdx.x;
    const int m0   = blockIdx.x * 128;     // m-tile == one t (128 batches)
    const int n0   = blockIdx.y * 128;
    const int w    = tid >> 6;
    const int lane = tid & 63;
    const int wm   = (w & 1) * 64;
    const int wn   = (w >> 1) * 64;
    const int lr   = lane & 15;
    const int kb   = (lane >> 4) * 8;

    f32x4 acc[4][4] = {};

    for (int k0 = 0; k0 < INDIM; k0 += 32) {
        __syncthreads();
        #pragma unroll
        for (int it = 0; it < 2; ++it) {
            int c   = tid + it * 256;      // 512 chunks of 8 halfs
            int row = c >> 2;
            int kp  = (c & 3) * 8;
            *(f16x8*)(As + row * 32 + kp) = *(const f16x8*)(A  + (size_t)(m0 + row) * INDIM + k0 + kp);
            *(f16x8*)(Bs + row * 32 + kp) = *(const f16x8*)(Bw + (size_t)(n0 + row) * INDIM + k0 + kp);
        }
        __syncthreads();
        f16x8 a[4], b[4];
        #pragma unroll
        for (int i = 0; i < 4; ++i) a[i] = *(const f16x8*)(As + (wm + i * 16 + lr) * 32 + kb);
        #pragma unroll
        for (int j = 0; j < 4; ++j) b[j] = *(const f16x8*)(Bs + (wn + j * 16 + lr) * 32 + kb);
        // swapped operands -> C row = n (gate row), col = m (batch)
        #pragma unroll
        for (int i = 0; i < 4; ++i)
            #pragma unroll
            for (int j = 0; j < 4; ++j)
                acc[i][j] = __builtin_amdgcn_mfma_f32_16x16x32_f16(b[j], a[i], acc[i][j], 0, 0, 0);
    }

    const int t  = blockIdx.x;
    const int lq = lane >> 4;
    #pragma unroll
    for (int i = 0; i < 4; ++i)
        #pragma unroll
        for (int j = 0; j < 4; ++j)
            #pragma unroll
            for (int r = 0; r < 4; ++r) {
                int n  = n0 + wn + j * 16 + lq * 4 + r;
                int bb = wm + i * 16 + lr;
                C[((size_t)t * NG + n) * BATCH + bb] = (half_t)acc[i][j][r];
            }
}

// ---------------- persistent bidirectional scan (one layer) ----------------
// grid = 200 single-wave blocks (PLAIN launch): dir (2) x batch-tile (4) x
// unit-group (25). Block owns 16 units x 32 batches. Sync group = the 25
// unit-group blocks of one (dir, batch-tile): independent chains, flag
// fan-in 25, no per-step __syncthreads, no cooperative API.
__global__ __launch_bounds__(64)
void scan_kernel(const float* __restrict__ Whh_all, const float* __restrict__ bih,
                 const float* __restrict__ bhh, const half_t* __restrict__ gates,
                 const int* __restrict__ bs, half_t* __restrict__ h_pub,
                 int* __restrict__ flags,
                 half_t* __restrict__ out16, float* __restrict__ out32, int layer) {
    __shared__ half_t Wsh[64][WSTR];

    const int tid = threadIdx.x;
    const int bid = blockIdx.x;
    const int d   = bid / (NCT * NGRP);
    const int rr  = bid % (NCT * NGRP);
    const int c   = rr / NGRP;
    const int g   = rr % NGRP;
    const int u0  = g * UPG;
    const int b0  = c * CT;
    const float* Wbase = Whh_all + (size_t)(layer * 2 + d) * 1600 * HID;

    // stage 64 Whh rows (type ty, unit u0+usub), fp32 -> fp16, zero-pad K
    for (int idx = tid; idx < 64 * KP; idx += 64) {
        int row = idx / KP, k = idx - row * KP;
        int ty = row >> 4, usub = row & 15;
        float v = (k < HID) ? Wbase[(size_t)(ty * HID + u0 + usub) * HID + k] : 0.f;
        Wsh[row][k] = (half_t)v;
    }

    const int lane = tid;
    const int lr = lane & 15, kq = (lane >> 4) * 8;
    const int bb = lane & 15, gg = lane >> 4;

    // biases for units u0 + 4gg + q (all 4 types)
    float bias[4][4];
    #pragma unroll
    for (int q = 0; q < 4; ++q)
        #pragma unroll
        for (int ty = 0; ty < 4; ++ty) {
            size_t bi = (size_t)(layer * 2 + d) * 1600 + ty * HID + u0 + 4 * gg + q;
            bias[q][ty] = bih[bi] + bhh[bi];
        }

    float c_reg[2][4] = {}, h_reg[2][4] = {};

    const long gstep = (long)(d ? -1 : 1) * (long)NG * BATCH;
    const long ostep = (long)(d ? -1 : 1) * (long)BATCH * 800;
    const int  t0p   = d ? (T_LEN - 1) : 0;
    const half_t* gptr = gates + (size_t)t0p * NG * BATCH + (size_t)d * 1600 * BATCH
                       + (size_t)(u0 + 4 * gg) * BATCH + b0 + bb;
    const size_t obase0 = (size_t)t0p * BATCH * 800 + (size_t)(b0 + bb) * 800
                        + (size_t)d * HID + u0 + 4 * gg;
    float*  op32 = out32 ? out32 + obase0 : (float*)nullptr;
    half_t* op16 = out16 ? out16 + obase0 : (half_t*)nullptr;

    // gate registers [j][q][ty], plain loads (compiler-managed waits)
    float gc[2][4][4], gn[2][4][4];
#define GPRE_LOAD(dstv, base) do {                                           \
        _Pragma("unroll") for (int j_ = 0; j_ < 2; ++j_)                     \
            _Pragma("unroll") for (int q_ = 0; q_ < 4; ++q_)                 \
                _Pragma("unroll") for (int ty_ = 0; ty_ < 4; ++ty_)          \
                    dstv[j_][q_][ty_] = (float)(base)[(size_t)ty_ * (HID * BATCH) \
                                                      + q_ * BATCH + 16 * j_];    \
    } while (0)

    __syncthreads();
    int bst = bs[t0p];
    GPRE_LOAD(gc, gptr);

    int* const myflag = flags + (d * NCT + c) * 32 + g;
    const int* const pollp = flags + (d * NCT + c) * 32 + lane;
    int cur = 0;

    for (int t = 0; t < T_LEN; ++t) {
        const bool last = (t == T_LEN - 1);
        const half_t* hcur = h_pub + (size_t)(cur * 2 + d) * BATCH * KP;

        // ---- coherent h loads for this block's batch tile ----
        const bool act0 = b0 < bst;
        const bool act1 = (b0 + 16) < bst;
        f32x4 hb0[13], hb1[13];
        const half_t* p0 = hcur + (size_t)(b0 + lr) * KP + kq;
        const half_t* p1 = p0 + 16 * KP;
        if (act0) {
            #pragma unroll
            for (int ks = 0; ks < 13; ++ks) hb0[ks] = ld_coh_128(p0 + ks * 32);
        }
        if (act1) {
            #pragma unroll
            for (int ks = 0; ks < 13; ++ks) hb1[ks] = ld_coh_128(p1 + ks * 32);
        }
        asm volatile("s_waitcnt vmcnt(0)" ::: "memory");
        __builtin_amdgcn_sched_barrier(0);

        // next-step batch count (tiny cached load; hides under MFMA)
        const int bst_next = last ? 0 : bs[d ? (T_LEN - 2 - t) : (t + 1)];

        // ---- MFMA: 64 gate rows (4 type-blocks) x 32 batches ----
        f32x4 acc[4][2] = {};
        if (act0) {
            #pragma unroll
            for (int ks = 0; ks < 13; ++ks) {
                f16x8 a0 = *(const f16x8*)(&Wsh[lr][kq + ks * 32]);
                f16x8 a1 = *(const f16x8*)(&Wsh[16 + lr][kq + ks * 32]);
                f16x8 a2 = *(const f16x8*)(&Wsh[32 + lr][kq + ks * 32]);
                f16x8 a3 = *(const f16x8*)(&Wsh[48 + lr][kq + ks * 32]);
                f16x8 bv0 = __builtin_bit_cast(f16x8, hb0[ks]);
                acc[0][0] = __builtin_amdgcn_mfma_f32_16x16x32_f16(a0, bv0, acc[0][0], 0, 0, 0);
                acc[1][0] = __builtin_amdgcn_mfma_f32_16x16x32_f16(a1, bv0, acc[1][0], 0, 0, 0);
                acc[2][0] = __builtin_amdgcn_mfma_f32_16x16x32_f16(a2, bv0, acc[2][0], 0, 0, 0);
                acc[3][0] = __builtin_amdgcn_mfma_f32_16x16x32_f16(a3, bv0, acc[3][0], 0, 0, 0);
                if (act1) {
                    f16x8 bv1 = __builtin_bit_cast(f16x8, hb1[ks]);
                    acc[0][1] = __builtin_amdgcn_mfma_f32_16x16x32_f16(a0, bv1, acc[0][1], 0, 0, 0);
                    acc[1][1] = __builtin_amdgcn_mfma_f32_16x16x32_f16(a1, bv1, acc[1][1], 0, 0, 0);
                    acc[2][1] = __builtin_amdgcn_mfma_f32_16x16x32_f16(a2, bv1, acc[2][1], 0, 0, 0);
                    acc[3][1] = __builtin_amdgcn_mfma_f32_16x16x32_f16(a3, bv1, acc[3][1], 0, 0, 0);
                }
            }
        }

        // ---- LSTM cell: lane owns batches {b0+bb, b0+16+bb} x units u0+4gg..+3
        half_t* hn = h_pub + (size_t)((cur ^ 1) * 2 + d) * BATCH * KP;
        #pragma unroll
        for (int j = 0; j < 2; ++j) {
            const int bj = b0 + 16 * j + bb;
            if (bj < bst) {
                #pragma unroll
                for (int q = 0; q < 4; ++q) {
                    float gI = acc[0][j][q] + gc[j][q][0] + bias[q][0];
                    float gF = acc[1][j][q] + gc[j][q][1] + bias[q][1];
                    float gG = acc[2][j][q] + gc[j][q][2] + bias[q][2];
                    float gO = acc[3][j][q] + gc[j][q][3] + bias[q][3];
                    float iv = 1.f / (1.f + __expf(-gI));
                    float fv = 1.f / (1.f + __expf(-gF));
                    float gv = 1.f - 2.f / (1.f + __expf(2.f * gG));
                    float ov = 1.f / (1.f + __expf(-gO));
                    float cn = fv * c_reg[j][q] + iv * gv;
                    float hnew = ov * (1.f - 2.f / (1.f + __expf(2.f * cn)));
                    c_reg[j][q] = cn; h_reg[j][q] = hnew;
                }
            }
            // publish rows the NEXT step will read (covers bwd activation: h=0)
            if (!last && bj < bst_next) {
                f16x4 hv4;
                hv4[0] = (half_t)h_reg[j][0]; hv4[1] = (half_t)h_reg[j][1];
                hv4[2] = (half_t)h_reg[j][2]; hv4[3] = (half_t)h_reg[j][3];
                st_coh_64(hn + (size_t)bj * KP + u0 + 4 * gg, __builtin_bit_cast(uint2v, hv4));
            }
        }

        // ---- drain h stores; signal this block's flag ----
        if (!last) {
            asm volatile("s_waitcnt vmcnt(0)" ::: "memory");
            if (lane == 0) st_coh_32(myflag, t + 1);
        }

        // ---- output stores + next gate prefetch (spin window) ----
        #pragma unroll
        for (int j = 0; j < 2; ++j) {
            const int bj = b0 + 16 * j + bb;
            const bool actj = bj < bst;
            if (op32) {
                f32x4 o4;
                #pragma unroll
                for (int q = 0; q < 4; ++q) o4[q] = actj ? h_reg[j][q] : 0.f;
                *(f32x4*)(op32 + (size_t)j * 16 * 800) = o4;
            } else {
                f16x4 o4;
                #pragma unroll
                for (int q = 0; q < 4; ++q) o4[q] = actj ? (half_t)h_reg[j][q] : (half_t)0.f;
                *(f16x4*)(op16 + (size_t)j * 16 * 800) = o4;
            }
        }
        if (op32) op32 += ostep; else op16 += ostep;

        if (!last) {
            gptr += gstep;
            GPRE_LOAD(gn, gptr);
            // drain outputs + prefetch so spin polls are clean
            asm volatile("s_waitcnt vmcnt(0)" ::: "memory");

            int pred;
            do {
                int v = (lane < NGRP) ? ld_coh_32(pollp) : 0x7fffffff;
                pred = (v >= t + 1);
            } while (!__all(pred));

            bst = bst_next;
            #pragma unroll
            for (int j = 0; j < 2; ++j)
                #pragma unroll
                for (int q = 0; q < 4; ++q)
                    #pragma unroll
                    for (int ty = 0; ty < 4; ++ty) gc[j][q][ty] = gn[j][q][ty];
        }
        cur ^= 1;
    }
#undef GPRE_LOAD
}

// ---------------- host ----------------
extern "C" void kernel_launch(void* const* d_in, const int* in_sizes, int n_in,
                              void* d_out, int out_size, void* d_ws, size_t ws_size,
                              hipStream_t stream) {
    const float* x    = (const float*)d_in[0];
    const float* Wih  = (const float*)d_in[1];
    const float* Whh  = (const float*)d_in[2];
    const float* bih  = (const float*)d_in[3];
    const float* bhh  = (const float*)d_in[4];
    const int*   bs   = (const int*)d_in[5];
    float*       out  = (float*)d_out;

    char* ws = (char*)d_ws;
    const size_t XBUF_B  = (size_t)T_LEN * BATCH * INDIM * 2;      // 104,857,600
    const size_t WIH_B   = (size_t)3 * 2 * 1600 * INDIM * 2;       //  15,360,000
    const size_t GATES_B = (size_t)T_LEN * NG * BATCH * 2;         // 419,430,400
    const size_t HPUB_B  = (size_t)2 * 2 * BATCH * KP * 2;         //     425,984

    half_t* xbuf0 = (half_t*)(ws);
    half_t* xbuf1 = (half_t*)(ws + XBUF_B);
    half_t* Wih16 = (half_t*)(ws + 2 * XBUF_B);
    half_t* gates = (half_t*)(ws + 2 * XBUF_B + WIH_B);
    half_t* h_pub = (half_t*)(ws + 2 * XBUF_B + WIH_B + GATES_B);
    int*    flags = (int*)   (ws + 2 * XBUF_B + WIH_B + GATES_B + HPUB_B);
    (void)ws_size; (void)in_sizes; (void)n_in; (void)out_size;

    cast_f32_f16<<<2048, 256, 0, stream>>>(x,   xbuf0, (size_t)T_LEN * BATCH * INDIM);
    cast_f32_f16<<<2048, 256, 0, stream>>>(Wih, Wih16, (size_t)3 * 2 * 1600 * INDIM);

    for (int l = 0; l < 3; ++l) {
        const half_t* xin    = (l == 0) ? xbuf0 : ((l == 1) ? xbuf1 : xbuf0);
        half_t*       xout16 = (l == 0) ? xbuf1 : ((l == 1) ? xbuf0 : (half_t*)nullptr);
        float*        out32  = (l == 2) ? out : (float*)nullptr;

        gemm_f16<<<dim3(512, 25), 256, 0, stream>>>(xin, Wih16 + (size_t)l * NG * INDIM, gates);

        // zero h double-buffers + flag arrays (8 groups x 32 ints)
        hipMemsetAsync(h_pub, 0, HPUB_B + 2048, stream);

        scan_kernel<<<dim3(2 * NCT * NGRP), dim3(64), 0, stream>>>(
            Whh, bih, bhh, gates, bs, h_pub, flags, xout16, out32, l);
    }
}

// Round 12
// 11174.821 us; speedup vs baseline: 1.2123x; 1.0043x over previous
//
#include <hip/hip_runtime.h>

typedef _Float16 half_t;
typedef _Float16 f16x8 __attribute__((ext_vector_type(8)));
typedef _Float16 f16x4 __attribute__((ext_vector_type(4)));
typedef float f32x4 __attribute__((ext_vector_type(4)));
typedef unsigned int u32x4 __attribute__((ext_vector_type(4)));
typedef unsigned int uint2v __attribute__((ext_vector_type(2)));

#define T_LEN 512
#define BATCH 128
#define INDIM 800
#define HID   400
#define NG    3200   // 2 dirs * 4H
#define KP    416    // recurrent K padded to 13*32
#define UPG   16     // units per block
#define NGRP  25     // unit-group blocks per (dir, batch-tile)
#define CT    32     // batch-tile size
#define NCT   4      // batch tiles
#define WSTR  424    // Wsh row stride in halfs (848 B: 16B-aligned for b128)
#define NSLOT 4

// coherent-at-LLC access (bypass L1+L2) -----------------------------------
__device__ __forceinline__ void st_coh_64(void* p, uint2v v) {
    asm volatile("global_store_dwordx2 %0, %1, off sc0 sc1" :: "v"(p), "v"(v) : "memory");
}
__device__ __forceinline__ void st_coh_128(void* p, u32x4 v) {
    asm volatile("global_store_dwordx4 %0, %1, off sc0 sc1" :: "v"(p), "v"(v) : "memory");
}
// coherent 16B load, NO internal wait; offset BEFORE cache flags (gfx950 syntax)
#define LDC(dst, p, off)                                                     \
    asm volatile("global_load_dwordx4 %0, %1, off offset:" #off " sc0 sc1"   \
                 : "=v"(dst) : "v"(p) : "memory")
// plain cached u16 load, result usable only after a vmcnt drain
#define GLD_U16(dst, ptr, offlit)                                            \
    asm volatile("global_load_ushort %0, %1, off offset:" #offlit            \
                 : "=v"(dst) : "v"(ptr) : "memory")

// ---------------- cast fp32 -> fp16 ----------------
__global__ void cast_f32_f16(const float* __restrict__ src, half_t* __restrict__ dst, size_t n) {
    size_t i = (size_t)blockIdx.x * blockDim.x + threadIdx.x;
    size_t stride = (size_t)gridDim.x * blockDim.x;
    for (; i < n; i += stride) dst[i] = (half_t)src[i];
}

// ---------------- input GEMM ----------------
// A[M=T*B, 800] @ W[3200, 800]^T, output TRANSPOSED per t-tile:
// gates_T[((t*3200)+n)*128 + b]   (fp16, fp32 accum)
__global__ __launch_bounds__(256)
void gemm_f16(const half_t* __restrict__ A, const half_t* __restrict__ Bw,
              half_t* __restrict__ C) {
    __shared__ half_t As[128 * 32];
    __shared__ half_t Bs[128 * 32];
    const int tid  = threadIdx.x;
    const int m0   = blockIdx.x * 128;     // m-tile == one t (128 batches)
    const int n0   = blockIdx.y * 128;
    const int w    = tid >> 6;
    const int lane = tid & 63;
    const int wm   = (w & 1) * 64;
    const int wn   = (w >> 1) * 64;
    const int lr   = lane & 15;
    const int kb   = (lane >> 4) * 8;

    f32x4 acc[4][4] = {};

    for (int k0 = 0; k0 < INDIM; k0 += 32) {
        __syncthreads();
        #pragma unroll
        for (int it = 0; it < 2; ++it) {
            int c   = tid + it * 256;      // 512 chunks of 8 halfs
            int row = c >> 2;
            int kp  = (c & 3) * 8;
            *(f16x8*)(As + row * 32 + kp) = *(const f16x8*)(A  + (size_t)(m0 + row) * INDIM + k0 + kp);
            *(f16x8*)(Bs + row * 32 + kp) = *(const f16x8*)(Bw + (size_t)(n0 + row) * INDIM + k0 + kp);
        }
        __syncthreads();
        f16x8 a[4], b[4];
        #pragma unroll
        for (int i = 0; i < 4; ++i) a[i] = *(const f16x8*)(As + (wm + i * 16 + lr) * 32 + kb);
        #pragma unroll
        for (int j = 0; j < 4; ++j) b[j] = *(const f16x8*)(Bs + (wn + j * 16 + lr) * 32 + kb);
        // swapped operands -> C row = n (gate row), col = m (batch)
        #pragma unroll
        for (int i = 0; i < 4; ++i)
            #pragma unroll
            for (int j = 0; j < 4; ++j)
                acc[i][j] = __builtin_amdgcn_mfma_f32_16x16x32_f16(b[j], a[i], acc[i][j], 0, 0, 0);
    }

    const int t  = blockIdx.x;
    const int lq = lane >> 4;
    #pragma unroll
    for (int i = 0; i < 4; ++i)
        #pragma unroll
        for (int j = 0; j < 4; ++j)
            #pragma unroll
            for (int r = 0; r < 4; ++r) {
                int n  = n0 + wn + j * 16 + lq * 4 + r;
                int bb = wm + i * 16 + lr;
                C[((size_t)t * NG + n) * BATCH + bb] = (half_t)acc[i][j][r];
            }
}

// ---------------- persistent bidirectional scan (one layer) ----------------
// grid = 200 single-wave blocks: dir (2) x batch-tile (4) x unit-group (25).
// NO flags: h published into 4 rotating sentinel-initialized slots; consumers
// poll the data itself (0xFFFF fp16 NaN sentinel = not yet written).
// Slot recycling is TILE-LOCAL: at step t each block re-sentinels ONLY its
// own 32 rows x 16-unit slice of slot (t+3)&3 — sync groups never touch each
// other's slot regions, so unbounded cross-tile drift is harmless.
__global__ __launch_bounds__(64)
void scan_kernel(const float* __restrict__ Whh_all, const float* __restrict__ bih,
                 const float* __restrict__ bhh, const half_t* __restrict__ gates,
                 const int* __restrict__ bs, half_t* __restrict__ h_pub,
                 half_t* __restrict__ out16, float* __restrict__ out32, int layer) {
    __shared__ half_t Wsh[64][WSTR];

    const int tid = threadIdx.x;
    const int bid = blockIdx.x;
    const int d   = bid / (NCT * NGRP);
    const int rr  = bid % (NCT * NGRP);
    const int c   = rr / NGRP;
    const int g   = rr % NGRP;
    const int u0  = g * UPG;
    const int b0  = c * CT;
    const float* Wbase = Whh_all + (size_t)(layer * 2 + d) * 1600 * HID;

    // stage 64 Whh rows (type ty, unit u0+usub), fp32 -> fp16, zero-pad K
    for (int idx = tid; idx < 64 * KP; idx += 64) {
        int row = idx / KP, k = idx - row * KP;
        int ty = row >> 4, usub = row & 15;
        float v = (k < HID) ? Wbase[(size_t)(ty * HID + u0 + usub) * HID + k] : 0.f;
        Wsh[row][k] = (half_t)v;
    }

    const int lane = tid;
    const int lr = lane & 15, kq = (lane >> 4) * 8;
    const int bb = lane & 15, gg = lane >> 4;

    // biases for units u0 + 4gg + q (all 4 types)
    float bias[4][4];
    #pragma unroll
    for (int q = 0; q < 4; ++q)
        #pragma unroll
        for (int ty = 0; ty < 4; ++ty) {
            size_t bi = (size_t)(layer * 2 + d) * 1600 + ty * HID + u0 + 4 * gg + q;
            bias[q][ty] = bih[bi] + bhh[bi];
        }

    float c_reg[2][4] = {}, h_reg[2][4] = {};

    const long gstep = (long)(d ? -1 : 1) * (long)NG * BATCH;
    const long ostep = (long)(d ? -1 : 1) * (long)BATCH * 800;
    const int  t0p   = d ? (T_LEN - 1) : 0;
    const half_t* gptr = gates + (size_t)t0p * NG * BATCH + (size_t)d * 1600 * BATCH
                       + (size_t)(u0 + 4 * gg) * BATCH + b0 + bb;
    const size_t obase0 = (size_t)t0p * BATCH * 800 + (size_t)(b0 + bb) * 800
                        + (size_t)d * HID + u0 + 4 * gg;
    float*  op32 = out32 ? out32 + obase0 : (float*)nullptr;
    half_t* op16 = out16 ? out16 + obase0 : (half_t*)nullptr;

    // tile-local sentinel target: row b0+(lane&31), 16B seg u0+(lane>>5)*8
    const size_t sent_off = (size_t)(b0 + (lane & 31)) * KP + u0 + (lane >> 5) * 8;

    // raw u16 gate regs [j][q][ty]
    int rawc[2][4][4];
#define GPRE_ISSUE(dstv, base) do {                                          \
        _Pragma("unroll") for (int ty_ = 0; ty_ < 4; ++ty_) {                \
            const half_t* pt_ = (base) + (size_t)ty_ * (HID * BATCH);        \
            GLD_U16(dstv[0][0][ty_], pt_, 0);   GLD_U16(dstv[1][0][ty_], pt_, 32);  \
            GLD_U16(dstv[0][1][ty_], pt_, 256); GLD_U16(dstv[1][1][ty_], pt_, 288); \
            GLD_U16(dstv[0][2][ty_], pt_, 512); GLD_U16(dstv[1][2][ty_], pt_, 544); \
            GLD_U16(dstv[0][3][ty_], pt_, 768); GLD_U16(dstv[1][3][ty_], pt_, 800); \
        }                                                                    \
    } while (0)

    // poll/load h for one slot: re-issue coherent loads until sentinel-free.
    f32x4 hb0[13], hb1[13];
#define POLL(slotbase) do {                                                  \
        const half_t* p0_ = (slotbase) + (size_t)(b0 + lr) * KP + kq;        \
        const half_t* p1_ = p0_ + 16 * KP;                                   \
        for (;;) {                                                           \
            LDC(hb0[0], p0_, 0);   LDC(hb0[1], p0_, 64);                     \
            LDC(hb0[2], p0_, 128); LDC(hb0[3], p0_, 192);                    \
            LDC(hb0[4], p0_, 256); LDC(hb0[5], p0_, 320);                    \
            LDC(hb0[6], p0_, 384); LDC(hb0[7], p0_, 448);                    \
            LDC(hb0[8], p0_, 512); LDC(hb0[9], p0_, 576);                    \
            LDC(hb0[10], p0_, 640); LDC(hb0[11], p0_, 704);                  \
            LDC(hb1[0], p1_, 0);   LDC(hb1[1], p1_, 64);                     \
            LDC(hb1[2], p1_, 128); LDC(hb1[3], p1_, 192);                    \
            LDC(hb1[4], p1_, 256); LDC(hb1[5], p1_, 320);                    \
            LDC(hb1[6], p1_, 384); LDC(hb1[7], p1_, 448);                    \
            LDC(hb1[8], p1_, 512); LDC(hb1[9], p1_, 576);                    \
            LDC(hb1[10], p1_, 640); LDC(hb1[11], p1_, 704);                  \
            if (kq < 16) { LDC(hb0[12], p0_, 768); LDC(hb1[12], p1_, 768); } \
            else { f32x4 z_ = {0.f, 0.f, 0.f, 0.f}; hb0[12] = z_; hb1[12] = z_; } \
            asm volatile("s_waitcnt vmcnt(0)" ::: "memory");                 \
            __builtin_amdgcn_sched_barrier(0);                               \
            unsigned m_ = 0u;                                                \
            _Pragma("unroll") for (int ks_ = 0; ks_ < 13; ++ks_) {           \
                u32x4 a_ = __builtin_bit_cast(u32x4, hb0[ks_]);              \
                u32x4 q_ = __builtin_bit_cast(u32x4, hb1[ks_]);              \
                _Pragma("unroll") for (int e_ = 0; e_ < 4; ++e_) {           \
                    m_ = m_ > a_[e_] ? m_ : a_[e_];                          \
                    m_ = m_ > q_[e_] ? m_ : q_[e_];                          \
                }                                                            \
            }                                                                \
            if (__all(m_ != 0xFFFFFFFFu)) break;                             \
        }                                                                    \
    } while (0)

    __syncthreads();
    int bst = bs[t0p];
    GPRE_ISSUE(rawc, gptr);                       // gates for t=0, in flight

    // prologue: load h_0 from slot 0 (zero-initialized -> passes immediately)
    POLL(h_pub + (size_t)d * BATCH * KP);

    for (int t = 0; t < T_LEN; ++t) {
        const bool last = (t == T_LEN - 1);

        // ---- re-sentinel MY TILE x MY UNITS of slot (t+3)&3 (group-local) ----
        {
            half_t* hs = h_pub + (size_t)((((t + 3) & 3) * 2) + d) * BATCH * KP;
            u32x4 sent = {~0u, ~0u, ~0u, ~0u};
            st_coh_128(hs + sent_off, sent);
        }

        const int bst_next = last ? bst : bs[d ? (T_LEN - 2 - t) : (t + 1)];

        // ---- MFMA: 64 gate rows (4 type-blocks) x 32 batches (act-gated) ----
        f32x4 acc[4][2] = {};
        if (b0 < bst) {
            const bool act1 = (b0 + 16) < bst;
            #pragma unroll
            for (int ks = 0; ks < 13; ++ks) {
                f16x8 a0 = *(const f16x8*)(&Wsh[lr][kq + ks * 32]);
                f16x8 a1 = *(const f16x8*)(&Wsh[16 + lr][kq + ks * 32]);
                f16x8 a2 = *(const f16x8*)(&Wsh[32 + lr][kq + ks * 32]);
                f16x8 a3 = *(const f16x8*)(&Wsh[48 + lr][kq + ks * 32]);
                f16x8 bv0 = __builtin_bit_cast(f16x8, hb0[ks]);
                acc[0][0] = __builtin_amdgcn_mfma_f32_16x16x32_f16(a0, bv0, acc[0][0], 0, 0, 0);
                acc[1][0] = __builtin_amdgcn_mfma_f32_16x16x32_f16(a1, bv0, acc[1][0], 0, 0, 0);
                acc[2][0] = __builtin_amdgcn_mfma_f32_16x16x32_f16(a2, bv0, acc[2][0], 0, 0, 0);
                acc[3][0] = __builtin_amdgcn_mfma_f32_16x16x32_f16(a3, bv0, acc[3][0], 0, 0, 0);
                if (act1) {
                    f16x8 bv1 = __builtin_bit_cast(f16x8, hb1[ks]);
                    acc[0][1] = __builtin_amdgcn_mfma_f32_16x16x32_f16(a0, bv1, acc[0][1], 0, 0, 0);
                    acc[1][1] = __builtin_amdgcn_mfma_f32_16x16x32_f16(a1, bv1, acc[1][1], 0, 0, 0);
                    acc[2][1] = __builtin_amdgcn_mfma_f32_16x16x32_f16(a2, bv1, acc[2][1], 0, 0, 0);
                    acc[3][1] = __builtin_amdgcn_mfma_f32_16x16x32_f16(a3, bv1, acc[3][1], 0, 0, 0);
                }
            }
        }

        // ---- drain: gates_t (needed now) + sentinel store (ordered pre-publish)
        asm volatile("s_waitcnt vmcnt(0)" ::: "memory");
        __builtin_amdgcn_sched_barrier(0);

        // ---- LSTM cell: lane owns batches {b0+bb, b0+16+bb} x units u0+4gg..+3
        #pragma unroll
        for (int j = 0; j < 2; ++j) {
            const int bj = b0 + 16 * j + bb;
            if (bj < bst) {
                #pragma unroll
                for (int q = 0; q < 4; ++q) {
                    float gI = acc[0][j][q] + (float)__builtin_bit_cast(half_t, (unsigned short)rawc[j][q][0]) + bias[q][0];
                    float gF = acc[1][j][q] + (float)__builtin_bit_cast(half_t, (unsigned short)rawc[j][q][1]) + bias[q][1];
                    float gG = acc[2][j][q] + (float)__builtin_bit_cast(half_t, (unsigned short)rawc[j][q][2]) + bias[q][2];
                    float gO = acc[3][j][q] + (float)__builtin_bit_cast(half_t, (unsigned short)rawc[j][q][3]) + bias[q][3];
                    float iv = 1.f / (1.f + __expf(-gI));
                    float fv = 1.f / (1.f + __expf(-gF));
                    float gv = 1.f - 2.f / (1.f + __expf(2.f * gG));
                    float ov = 1.f / (1.f + __expf(-gO));
                    float cn = fv * c_reg[j][q] + iv * gv;
                    float hnew = ov * (1.f - 2.f / (1.f + __expf(2.f * cn)));
                    c_reg[j][q] = cn; h_reg[j][q] = hnew;
                }
            }
        }

        // ---- publish h_{t+1} into slot (t+1)&3 — ALL my rows, no drain/flag
        {
            half_t* hn = h_pub + (size_t)((((t + 1) & 3) * 2) + d) * BATCH * KP;
            #pragma unroll
            for (int j = 0; j < 2; ++j) {
                const int bj = b0 + 16 * j + bb;
                f16x4 hv4;
                hv4[0] = (half_t)h_reg[j][0]; hv4[1] = (half_t)h_reg[j][1];
                hv4[2] = (half_t)h_reg[j][2]; hv4[3] = (half_t)h_reg[j][3];
                st_coh_64(hn + (size_t)bj * KP + u0 + 4 * gg, __builtin_bit_cast(uint2v, hv4));
            }
        }

        // ---- output stores (masked zeros for inactive rows) ----
        #pragma unroll
        for (int j = 0; j < 2; ++j) {
            const int bj = b0 + 16 * j + bb;
            const bool actj = bj < bst;
            if (op32) {
                f32x4 o4;
                #pragma unroll
                for (int q = 0; q < 4; ++q) o4[q] = actj ? h_reg[j][q] : 0.f;
                *(f32x4*)(op32 + (size_t)j * 16 * 800) = o4;
            } else {
                f16x4 o4;
                #pragma unroll
                for (int q = 0; q < 4; ++q) o4[q] = actj ? (half_t)h_reg[j][q] : (half_t)0.f;
                *(f16x4*)(op16 + (size_t)j * 16 * 800) = o4;
            }
        }
        if (op32) op32 += ostep; else op16 += ostep;

        // ---- tail: issue next gates (overlaps poll), then poll slot (t+1)&3
        if (!last) {
            gptr += gstep;
            GPRE_ISSUE(rawc, gptr);
            POLL(h_pub + (size_t)((((t + 1) & 3) * 2) + d) * BATCH * KP);
            bst = bst_next;
        }
    }
#undef GPRE_ISSUE
#undef POLL
}

// ---------------- host ----------------
extern "C" void kernel_launch(void* const* d_in, const int* in_sizes, int n_in,
                              void* d_out, int out_size, void* d_ws, size_t ws_size,
                              hipStream_t stream) {
    const float* x    = (const float*)d_in[0];
    const float* Wih  = (const float*)d_in[1];
    const float* Whh  = (const float*)d_in[2];
    const float* bih  = (const float*)d_in[3];
    const float* bhh  = (const float*)d_in[4];
    const int*   bs   = (const int*)d_in[5];
    float*       out  = (float*)d_out;

    char* ws = (char*)d_ws;
    const size_t XBUF_B  = (size_t)T_LEN * BATCH * INDIM * 2;      // 104,857,600
    const size_t WIH_B   = (size_t)3 * 2 * 1600 * INDIM * 2;       //  15,360,000
    const size_t GATES_B = (size_t)T_LEN * NG * BATCH * 2;         // 419,430,400
    const size_t SLOT_B  = (size_t)2 * BATCH * KP * 2;             //     212,992

    half_t* xbuf0 = (half_t*)(ws);
    half_t* xbuf1 = (half_t*)(ws + XBUF_B);
    half_t* Wih16 = (half_t*)(ws + 2 * XBUF_B);
    half_t* gates = (half_t*)(ws + 2 * XBUF_B + WIH_B);
    half_t* h_pub = (half_t*)(ws + 2 * XBUF_B + WIH_B + GATES_B);
    (void)ws_size; (void)in_sizes; (void)n_in; (void)out_size;

    cast_f32_f16<<<2048, 256, 0, stream>>>(x,   xbuf0, (size_t)T_LEN * BATCH * INDIM);
    cast_f32_f16<<<2048, 256, 0, stream>>>(Wih, Wih16, (size_t)3 * 2 * 1600 * INDIM);

    for (int l = 0; l < 3; ++l) {
        const half_t* xin    = (l == 0) ? xbuf0 : ((l == 1) ? xbuf1 : xbuf0);
        half_t*       xout16 = (l == 0) ? xbuf1 : ((l == 1) ? xbuf0 : (half_t*)nullptr);
        float*        out32  = (l == 2) ? out : (float*)nullptr;

        gemm_f16<<<dim3(512, 25), 256, 0, stream>>>(xin, Wih16 + (size_t)l * NG * INDIM, gates);

        // slot 0 = h_0 zeros; slots 1..3 = 0xFFFF sentinel
        hipMemsetAsync(h_pub, 0, SLOT_B, stream);
        hipMemsetAsync((char*)h_pub + SLOT_B, 0xFF, (NSLOT - 1) * SLOT_B, stream);

        scan_kernel<<<dim3(2 * NCT * NGRP), dim3(64), 0, stream>>>(
            Whh, bih, bhh, gates, bs, h_pub, xout16, out32, l);
    }
}